// Round 7
// baseline (108.888 us; speedup 1.0000x reference)
//
#include <hip/hip_runtime.h>
#include <math.h>

#define DIM 4096
#define NQ 12
#define BATCH 128
#define BN 32
#define BK 64
#define ZSTR (128 * DIM)   // floats per split-k slab

typedef __attribute__((ext_vector_type(8))) short bf16x8;
typedef __attribute__((ext_vector_type(4))) float f32x4;
typedef unsigned int uint2v __attribute__((ext_vector_type(2)));

__device__ __forceinline__ unsigned short f2bf(float f) {
    union { float f; unsigned int u; } c; c.f = f;
    unsigned int u = c.u;
    unsigned int r = u + 0x7fffu + ((u >> 16) & 1u);   // RNE (finite inputs)
    return (unsigned short)(r >> 16);
}

// ---------------------------------------------------------------------------
// Kernel 1: split-K bf16 MFMA GEMM with register prefetch double-buffering.
// psum[z][m][n] = A[m, kz] @ W[n, kz]^T ; BM=128, BN=32, BK=64, 4 waves.
// ---------------------------------------------------------------------------
__global__ __launch_bounds__(256) void gemm_bf16_kernel(
    const float* __restrict__ A, const float* __restrict__ W,
    float* __restrict__ psum, int splitk)
{
    __shared__ unsigned short As[128][BK + 8];
    __shared__ unsigned short Bs[BN][BK + 8];

    const int t  = threadIdx.x;
    const int bn = blockIdx.x * BN;
    const int z  = blockIdx.y;
    const int krange = DIM / splitk;
    const int kstart = z * krange;
    const int kend = kstart + krange;
    const int w = t >> 6;
    const int l = t & 63;
    const int m0w = w * 32;

    f32x4 acc[2][2] = {};
    float4 pa[8], pb[2];

    auto load_tiles = [&](int k0) {
#pragma unroll
        for (int i = 0; i < 8; ++i) {
            const int fid = t + i * 256;
            pa[i] = *(const float4*)(A + (size_t)(fid >> 4) * DIM + k0 + (fid & 15) * 4);
        }
#pragma unroll
        for (int i = 0; i < 2; ++i) {
            const int fid = t + i * 256;
            pb[i] = *(const float4*)(W + (size_t)(bn + (fid >> 4)) * DIM + k0 + (fid & 15) * 4);
        }
    };

    load_tiles(kstart);
    for (int k0 = kstart; k0 < kend; k0 += BK) {
        __syncthreads();
#pragma unroll
        for (int i = 0; i < 8; ++i) {
            const int fid = t + i * 256;
            const int row = fid >> 4, c4 = (fid & 15) * 4;
            union { unsigned short h[4]; uint2 u; } pk;
            pk.h[0] = f2bf(pa[i].x); pk.h[1] = f2bf(pa[i].y);
            pk.h[2] = f2bf(pa[i].z); pk.h[3] = f2bf(pa[i].w);
            *(uint2*)&As[row][c4] = pk.u;
        }
#pragma unroll
        for (int i = 0; i < 2; ++i) {
            const int fid = t + i * 256;
            const int row = fid >> 4, c4 = (fid & 15) * 4;
            union { unsigned short h[4]; uint2 u; } pk;
            pk.h[0] = f2bf(pb[i].x); pk.h[1] = f2bf(pb[i].y);
            pk.h[2] = f2bf(pb[i].z); pk.h[3] = f2bf(pb[i].w);
            *(uint2*)&Bs[row][c4] = pk.u;
        }
        const int kn = (k0 + BK < kend) ? (k0 + BK) : k0;
        load_tiles(kn);
        __syncthreads();
#pragma unroll
        for (int kk = 0; kk < 2; ++kk) {
            const int kc = kk * 32 + (l >> 4) * 8;
            bf16x8 a0 = *(const bf16x8*)&As[m0w +      (l & 15)][kc];
            bf16x8 a1 = *(const bf16x8*)&As[m0w + 16 + (l & 15)][kc];
            bf16x8 b0 = *(const bf16x8*)&Bs[      (l & 15)][kc];
            bf16x8 b1 = *(const bf16x8*)&Bs[16 + (l & 15)][kc];
            acc[0][0] = __builtin_amdgcn_mfma_f32_16x16x32_bf16(a0, b0, acc[0][0], 0, 0, 0);
            acc[0][1] = __builtin_amdgcn_mfma_f32_16x16x32_bf16(a0, b1, acc[0][1], 0, 0, 0);
            acc[1][0] = __builtin_amdgcn_mfma_f32_16x16x32_bf16(a1, b0, acc[1][0], 0, 0, 0);
            acc[1][1] = __builtin_amdgcn_mfma_f32_16x16x32_bf16(a1, b1, acc[1][1], 0, 0, 0);
        }
    }
#pragma unroll
    for (int mf = 0; mf < 2; ++mf)
#pragma unroll
        for (int nf = 0; nf < 2; ++nf)
#pragma unroll
            for (int r = 0; r < 4; ++r) {
                const int m = m0w + mf * 16 + (l >> 4) * 4 + r;
                const int n = bn + nf * 16 + (l & 15);
                psum[(size_t)z * ZSTR + (size_t)m * DIM + n] = acc[mf][nf][r];
            }
}

// ---------------------------------------------------------------------------
// lane-exchange primitives (VALU pipe, zero DS)
// ---------------------------------------------------------------------------
template<int CTRL>
__device__ __forceinline__ float fdpp(float v) {
    return __int_as_float(__builtin_amdgcn_update_dpp(
        0, __float_as_int(v), CTRL, 0xF, 0xF, false));
}
__device__ __forceinline__ float pl16_partner(float v) {
#if __has_builtin(__builtin_amdgcn_permlane16_swap)
    uint2v r = __builtin_amdgcn_permlane16_swap(__float_as_uint(v), __float_as_uint(v), false, false);
    return __uint_as_float(r.x ^ r.y ^ __float_as_uint(v));
#else
    float a = v, b = v;
    asm volatile("v_permlane16_swap_b32 %0, %1" : "+v"(a), "+v"(b));
    return __uint_as_float(__float_as_uint(a) ^ __float_as_uint(b) ^ __float_as_uint(v));
#endif
}
__device__ __forceinline__ float pl32_partner(float v) {
#if __has_builtin(__builtin_amdgcn_permlane32_swap)
    uint2v r = __builtin_amdgcn_permlane32_swap(__float_as_uint(v), __float_as_uint(v), false, false);
    return __uint_as_float(r.x ^ r.y ^ __float_as_uint(v));
#else
    float a = v, b = v;
    asm volatile("v_permlane32_swap_b32 %0, %1" : "+v"(a), "+v"(b));
    return __uint_as_float(__float_as_uint(a) ^ __float_as_uint(b) ^ __float_as_uint(v));
#endif
}

// ---------------------------------------------------------------------------
// LDS bank swizzles — designed for the 16-lane-phase model: every group of 16
// consecutive lanes must map bijectively onto the 16 bank-pairs (slot[3:0]).
// slot = s ^ A.s[11:4] with per-buffer/per-layer tap matrices A, verified
// group-rank-4 for all access patterns (see round theory for the derivation):
//   f0 (buf0, T):      a4=1 a5=2 a10=4 a11=8
//   f1 l=0 (r=1 T'):   a4=1 a5=3 a10=4 a11=8
//   f1 l=1 (r=2 T'):   a4=3 a5=1 a10=4 a11=8
//   f1 l=2 (r=3 T'):   a4=1 a5=2 a8=1 a10=4 a11=8
//   f1 l=3 (r=4 T'):   a4=2 a5=3 a6=4 a7=8 a10=4 a11=8
// Packed nibble encoding (a_{4+k} at nibble k):
#define F0SWZ(x) ((x) ^ (((x) >> 4) & 3) ^ ((((x) >> 10) & 3) << 2))
__device__ __forceinline__ int f1swz(unsigned int pack, int x) {
    int low = 0;
#pragma unroll
    for (int k = 0; k < 8; ++k)
        low ^= (-((x >> (4 + k)) & 1)) & (int)((pack >> (4 * k)) & 15u);
    return x ^ low;
}

// ---------------------------------------------------------------------------
// Kernel 2: fused reduce+GELU+norm + quantum circuit. 1024 threads, 4 amps.
// M0: state = (wv<<8)|(l6<<2)|j.
// Layer = epoch A (M0: DPP/permlane gates b2..b7, reg gates b0,b1)
//       + T  (M0->M1 via buf0/f0: j<->b8,9 ; l6[1:0]<->b10,11)
//       + epoch B (M1: DPP gates b10,b11, reg gates b8,b9)
//       + T' (M1->M0 via buf1/f1_l with the 12-CNOT perm folded into the read).
// ---------------------------------------------------------------------------
__global__ __launch_bounds__(1024, 4) void circuit_kernel(
    const float* __restrict__ psum, int splitk, const float* __restrict__ bias,
    const float* __restrict__ qw, const float* __restrict__ Wfc,
    const float* __restrict__ bfc, float* __restrict__ out)
{
    __shared__ float2 sbuf[2][4096];   // 64 KB: buf0 for T, buf1 for T'
    __shared__ float4 gsel[48][2];     // [g][bsel]: (own_r,own_i,par_r,par_i)
    __shared__ float4 grow1[48];       // (u10r,u10i,u11r,u11i)
    __shared__ float redw[16];
    __shared__ float zred[16][12];
    __shared__ float zbit[12];

    const int t = threadIdx.x;
    const int b = blockIdx.x;
    const int wv = t >> 6;
    const int l6 = t & 63;
    const int w01 = wv & 3;
    const int w23 = wv >> 2;

    const unsigned int APACK[4] = {0x84000031u, 0x84000013u, 0x84010021u, 0x84008432u};

    if (t < 48) {
        const int base = t * 3;
        const float phi = qw[base + 0], th = qw[base + 1], om = qw[base + 2];
        float c, s, chp, shp, chm, shm;
        sincosf(0.5f * th, &s, &c);
        sincosf(0.5f * (phi + om), &shp, &chp);
        sincosf(0.5f * (phi - om), &shm, &chm);
        const float u00r =  c * chp, u00i = -c * shp;
        const float u01r = -s * chm, u01i = -s * shm;
        const float u10r =  s * chm, u10i = -s * shm;
        const float u11r =  c * chp, u11i =  c * shp;
        gsel[t][0] = make_float4(u00r, u00i, u01r, u01i);
        gsel[t][1] = make_float4(u11r, u11i, u10r, u10i);
        grow1[t]   = make_float4(u10r, u10i, u11r, u11i);
    }

    // per-thread CNOT-perm images (f1_l-transformed), registers, static-indexed
    int ssfb[4], sspjv[4][4], fwb[4];
    const int s0base = (wv << 8) | (l6 << 2);
    const int s1base = ((l6 & 3) << 10) | ((l6 >> 2) << 4) | (w23 << 2) | w01;
#pragma unroll
    for (int ll = 0; ll < 4; ++ll) {
        const int r = ll + 1;
        int u = s0base;
        for (int q = 11; q >= 0; --q) {
            const int bc = 11 - q, bt2 = 11 - ((q + r) % 12);
            u ^= ((u >> bc) & 1) << bt2;
        }
        ssfb[ll] = f1swz(APACK[ll], u);
        fwb[ll]  = f1swz(APACK[ll], s1base);
        sspjv[ll][0] = 0;
#pragma unroll
        for (int j = 1; j < 4; ++j) {
            int v = j;
            for (int q = 11; q >= 0; --q) {
                const int bc = 11 - q, bt2 = 11 - ((q + r) % 12);
                v ^= ((v >> bc) & 1) << bt2;
            }
            sspjv[ll][j] = f1swz(APACK[ll], v);
        }
    }

    // transition slot bases (f0 taps: bits 4,5 -> [1:0], bits 10,11 -> [3:2];
    // j passes through untouched in both uses)
    const int base0 = F0SWZ(s0base);   // T write: base0 ^ j
    const int base1 = F0SWZ(s1base);   // T read:  base1 ^ (j<<8)

    const int bs0 = l6 & 1, bs1 = (l6 >> 1) & 1, bs2 = (l6 >> 2) & 1;
    const int bs3 = (l6 >> 3) & 1, bs4 = (l6 >> 4) & 1, bs5 = (l6 >> 5) & 1;

    // ---- fused split-K reduce + bias + exact GELU + norm ----
    float a0 = 0.f, a1 = 0.f, a2 = 0.f, a3 = 0.f;
    for (int z = 0; z < splitk; ++z) {
        const float4 p = *(const float4*)(psum + (size_t)z * ZSTR + (size_t)b * DIM + t * 4);
        a0 += p.x; a1 += p.y; a2 += p.z; a3 += p.w;
    }
    {
        const float4 bb = *(const float4*)(bias + t * 4);
        a0 += bb.x; a1 += bb.y; a2 += bb.z; a3 += bb.w;
    }
    float xr[4];
    xr[0] = 0.5f * a0 * (1.0f + erff(a0 * 0.70710678118654752f));
    xr[1] = 0.5f * a1 * (1.0f + erff(a1 * 0.70710678118654752f));
    xr[2] = 0.5f * a2 * (1.0f + erff(a2 * 0.70710678118654752f));
    xr[3] = 0.5f * a3 * (1.0f + erff(a3 * 0.70710678118654752f));
    float ss = xr[0]*xr[0] + xr[1]*xr[1] + xr[2]*xr[2] + xr[3]*xr[3];
#pragma unroll
    for (int off = 32; off; off >>= 1) ss += __shfl_xor(ss, off);
    if (l6 == 0) redw[wv] = ss;
    __syncthreads();
    float tot = 0.f;
#pragma unroll
    for (int i = 0; i < 16; ++i) tot += redw[i];
    const float rn = 1.0f / sqrtf(tot);

    float sr[4], si[4];
#pragma unroll
    for (int j = 0; j < 4; ++j) { sr[j] = xr[j] * rn; si[j] = 0.f; }

    auto reg_gate = [&](int lb, float4 g0, float4 g1) {
#pragma unroll
        for (int p = 0; p < 2; ++p) {
            const int j0 = (lb == 0) ? (p << 1) : p;
            const int j1 = j0 | (1 << lb);
            const float ar = sr[j0], ai = si[j0];
            const float br = sr[j1], bi = si[j1];
            sr[j0] = g0.x * ar - g0.y * ai + g0.z * br - g0.w * bi;
            si[j0] = g0.x * ai + g0.y * ar + g0.z * bi + g0.w * br;
            sr[j1] = g1.x * ar - g1.y * ai + g1.z * br - g1.w * bi;
            si[j1] = g1.x * ai + g1.y * ar + g1.z * bi + g1.w * br;
        }
    };
    auto lane_gate = [&](auto&& partner, float4 gs) {
#pragma unroll
        for (int j = 0; j < 4; ++j) {
            const float pr = partner(sr[j]), pi = partner(si[j]);
            const float nr = gs.x * sr[j] - gs.y * si[j] + gs.z * pr - gs.w * pi;
            const float ni = gs.x * si[j] + gs.y * sr[j] + gs.z * pi + gs.w * pr;
            sr[j] = nr; si[j] = ni;
        }
    };

    for (int rep = 0; rep < 4; ++rep) {
#pragma unroll
        for (int l = 0; l < 4; ++l) {
            const int gb = l * 12;
            // hoisted coefficient loads (broadcast, batched ds_reads)
            const float4 gA2 = gsel[gb + 9][bs0], gA3 = gsel[gb + 8][bs1];
            const float4 gA4 = gsel[gb + 7][bs2], gA5 = gsel[gb + 6][bs3];
            const float4 gA6 = gsel[gb + 5][bs4], gA7 = gsel[gb + 4][bs5];
            const float4 rAa0 = gsel[gb + 11][0], rAb0 = grow1[gb + 11];
            const float4 rAa1 = gsel[gb + 10][0], rAb1 = grow1[gb + 10];
            // ---- epoch A (M0): lane gates b2..b7 (q9..q4), reg b0,b1 (q11,q10)
            lane_gate([](float v) { return fdpp<0xB1>(v); },               gA2);
            lane_gate([](float v) { return fdpp<0x4E>(v); },               gA3);
            lane_gate([](float v) { return fdpp<0x1B>(fdpp<0x141>(v)); },  gA4);
            lane_gate([](float v) { return fdpp<0x141>(fdpp<0x140>(v)); }, gA5);
            lane_gate([](float v) { return pl16_partner(v); },             gA6);
            lane_gate([](float v) { return pl32_partner(v); },             gA7);
            reg_gate(0, rAa0, rAb0);
            reg_gate(1, rAa1, rAb1);
            // ---- T: M0 -> M1 (buf0, f0) ----
#pragma unroll
            for (int j = 0; j < 4; ++j)
                sbuf[0][base0 ^ j] = make_float2(sr[j], si[j]);
            __syncthreads();
#pragma unroll
            for (int j = 0; j < 4; ++j) {
                float2 a = sbuf[0][base1 ^ (j << 8)];
                sr[j] = a.x; si[j] = a.y;
            }
            // ---- epoch B (M1): DPP gates b10(q1),b11(q0); reg b8(q3),b9(q2)
            const float4 gB0 = gsel[gb + 1][bs0], gB1 = gsel[gb + 0][bs1];
            const float4 rBa0 = gsel[gb + 3][0], rBb0 = grow1[gb + 3];
            const float4 rBa1 = gsel[gb + 2][0], rBb1 = grow1[gb + 2];
            lane_gate([](float v) { return fdpp<0xB1>(v); }, gB0);
            lane_gate([](float v) { return fdpp<0x4E>(v); }, gB1);
            reg_gate(0, rBa0, rBb0);
            reg_gate(1, rBa1, rBb1);
            // ---- T': M1 -> M0 + CNOT fold (buf1, f1_l) ----
            // f1_l(j<<8): only l=2 has a tap from bit 8 (a8=1)
#pragma unroll
            for (int j = 0; j < 4; ++j)
                sbuf[1][fwb[l] ^ (j << 8) ^ ((l == 2) ? (j & 1) : 0)] = make_float2(sr[j], si[j]);
            __syncthreads();
#pragma unroll
            for (int j = 0; j < 4; ++j) {
                float2 a = sbuf[1][ssfb[l] ^ sspjv[l][j]];
                sr[j] = a.x; si[j] = a.y;
            }
        }
    }

    // ---- <Z_bp> partials (M0: bits >=2 thread-uniform, d = t*4+j) ----
    const float p0 = sr[0]*sr[0] + si[0]*si[0];
    const float p1 = sr[1]*sr[1] + si[1]*si[1];
    const float p2 = sr[2]*sr[2] + si[2]*si[2];
    const float p3 = sr[3]*sr[3] + si[3]*si[3];
    const float psumv = p0 + p1 + p2 + p3;
    float zp[12];
    zp[0] = p0 - p1 + p2 - p3;
    zp[1] = p0 + p1 - p2 - p3;
#pragma unroll
    for (int bp = 2; bp < 12; ++bp)
        zp[bp] = ((t >> (bp - 2)) & 1) ? -psumv : psumv;
#pragma unroll
    for (int bp = 0; bp < 12; ++bp) {
        float vv = zp[bp];
#pragma unroll
        for (int off = 32; off; off >>= 1) vv += __shfl_xor(vv, off);
        if (l6 == 0) zred[wv][bp] = vv;
    }
    __syncthreads();
    if (t < 12) {
        float vv = 0.f;
#pragma unroll
        for (int w2 = 0; w2 < 16; ++w2) vv += zred[w2][t];
        zbit[t] = vv;
    }
    __syncthreads();
    if (t < 10) {
        float o = bfc[t];
#pragma unroll
        for (int q = 0; q < NQ; ++q) o = fmaf(zbit[11 - q], Wfc[t * NQ + q], o);
        out[b * 10 + t] = o;
    }
}

extern "C" void kernel_launch(void* const* d_in, const int* in_sizes, int n_in,
                              void* d_out, int out_size, void* d_ws, size_t ws_size,
                              hipStream_t stream)
{
    const float* inputs = (const float*)d_in[0];   // 128 x 4096
    const float* W_pre  = (const float*)d_in[1];   // 4096 x 4096
    const float* b_pre  = (const float*)d_in[2];   // 4096
    const float* q_w    = (const float*)d_in[3];   // 4 x 12 x 3
    const float* W_fc   = (const float*)d_in[4];   // 10 x 12
    const float* b_fc   = (const float*)d_in[5];   // 10
    float* outp = (float*)d_out;                   // 128 x 10
    float* psum = (float*)d_ws;                    // splitk x 128 x 4096 f32

    const size_t slab = (size_t)ZSTR * sizeof(float);   // 2 MB
    int splitk = 4;
    if (ws_size < 4 * slab) splitk = 2;
    if (ws_size < 2 * slab) splitk = 1;

    dim3 g1(DIM / BN, splitk);
    gemm_bf16_kernel<<<g1, 256, 0, stream>>>(inputs, W_pre, psum, splitk);
    circuit_kernel<<<BATCH, 1024, 0, stream>>>(psum, splitk, b_pre, q_w, W_fc, b_fc, outp);
}

// Round 8
// 104.840 us; speedup vs baseline: 1.0386x; 1.0386x over previous
//
#include <hip/hip_runtime.h>
#include <hip/hip_bf16.h>
#include <math.h>

#define DIM 4096
#define NQ 12
#define BATCH 128
#define BN 32
#define BK 64
#define ZSTR (128 * DIM)   // floats per split-k slab

typedef __attribute__((ext_vector_type(8))) short bf16x8;
typedef __attribute__((ext_vector_type(4))) float f32x4;
typedef unsigned int uint2v __attribute__((ext_vector_type(2)));

// pair-convert f32x4 -> 4 bf16 via v_cvt_pk_bf16_f32 (RNE)
__device__ __forceinline__ uint2 cvt4bf(float4 v) {
    union { __hip_bfloat162 h2[2]; uint2 u; } pk;
    pk.h2[0] = __float22bfloat162_rn(make_float2(v.x, v.y));
    pk.h2[1] = __float22bfloat162_rn(make_float2(v.z, v.w));
    return pk.u;
}

// ---------------------------------------------------------------------------
// Kernel 1: split-K bf16 MFMA GEMM with register prefetch double-buffering.
// psum[z][m][n] = A[m, kz] @ W[n, kz]^T ; BM=128, BN=32, BK=64, 4 waves.
// ---------------------------------------------------------------------------
__global__ __launch_bounds__(256) void gemm_bf16_kernel(
    const float* __restrict__ A, const float* __restrict__ W,
    float* __restrict__ psum, int splitk)
{
    __shared__ unsigned short As[128][BK + 8];
    __shared__ unsigned short Bs[BN][BK + 8];

    const int t  = threadIdx.x;
    const int bn = blockIdx.x * BN;
    const int z  = blockIdx.y;
    const int krange = DIM / splitk;
    const int kstart = z * krange;
    const int kend = kstart + krange;
    const int w = t >> 6;
    const int l = t & 63;
    const int m0w = w * 32;

    f32x4 acc[2][2] = {};
    float4 pa[8], pb[2];

    auto load_tiles = [&](int k0) {
#pragma unroll
        for (int i = 0; i < 8; ++i) {
            const int fid = t + i * 256;
            pa[i] = *(const float4*)(A + (size_t)(fid >> 4) * DIM + k0 + (fid & 15) * 4);
        }
#pragma unroll
        for (int i = 0; i < 2; ++i) {
            const int fid = t + i * 256;
            pb[i] = *(const float4*)(W + (size_t)(bn + (fid >> 4)) * DIM + k0 + (fid & 15) * 4);
        }
    };

    load_tiles(kstart);
    for (int k0 = kstart; k0 < kend; k0 += BK) {
        __syncthreads();
#pragma unroll
        for (int i = 0; i < 8; ++i) {
            const int fid = t + i * 256;
            *(uint2*)&As[fid >> 4][(fid & 15) * 4] = cvt4bf(pa[i]);
        }
#pragma unroll
        for (int i = 0; i < 2; ++i) {
            const int fid = t + i * 256;
            *(uint2*)&Bs[fid >> 4][(fid & 15) * 4] = cvt4bf(pb[i]);
        }
        const int kn = (k0 + BK < kend) ? (k0 + BK) : k0;
        load_tiles(kn);
        __syncthreads();
#pragma unroll
        for (int kk = 0; kk < 2; ++kk) {
            const int kc = kk * 32 + (l >> 4) * 8;
            bf16x8 a0 = *(const bf16x8*)&As[m0w +      (l & 15)][kc];
            bf16x8 a1 = *(const bf16x8*)&As[m0w + 16 + (l & 15)][kc];
            bf16x8 b0 = *(const bf16x8*)&Bs[      (l & 15)][kc];
            bf16x8 b1 = *(const bf16x8*)&Bs[16 + (l & 15)][kc];
            acc[0][0] = __builtin_amdgcn_mfma_f32_16x16x32_bf16(a0, b0, acc[0][0], 0, 0, 0);
            acc[0][1] = __builtin_amdgcn_mfma_f32_16x16x32_bf16(a0, b1, acc[0][1], 0, 0, 0);
            acc[1][0] = __builtin_amdgcn_mfma_f32_16x16x32_bf16(a1, b0, acc[1][0], 0, 0, 0);
            acc[1][1] = __builtin_amdgcn_mfma_f32_16x16x32_bf16(a1, b1, acc[1][1], 0, 0, 0);
        }
    }
#pragma unroll
    for (int mf = 0; mf < 2; ++mf)
#pragma unroll
        for (int nf = 0; nf < 2; ++nf)
#pragma unroll
            for (int r = 0; r < 4; ++r) {
                const int m = m0w + mf * 16 + (l >> 4) * 4 + r;
                const int n = bn + nf * 16 + (l & 15);
                psum[(size_t)z * ZSTR + (size_t)m * DIM + n] = acc[mf][nf][r];
            }
}

// ---------------------------------------------------------------------------
// lane-exchange primitives (VALU pipe, zero DS)
// ---------------------------------------------------------------------------
template<int CTRL>
__device__ __forceinline__ float fdpp(float v) {
    return __int_as_float(__builtin_amdgcn_update_dpp(
        0, __float_as_int(v), CTRL, 0xF, 0xF, false));
}
__device__ __forceinline__ float pl16_partner(float v) {
#if __has_builtin(__builtin_amdgcn_permlane16_swap)
    uint2v r = __builtin_amdgcn_permlane16_swap(__float_as_uint(v), __float_as_uint(v), false, false);
    return __uint_as_float(r.x ^ r.y ^ __float_as_uint(v));
#else
    float a = v, b = v;
    asm volatile("v_permlane16_swap_b32 %0, %1" : "+v"(a), "+v"(b));
    return __uint_as_float(__float_as_uint(a) ^ __float_as_uint(b) ^ __float_as_uint(v));
#endif
}
__device__ __forceinline__ float pl32_partner(float v) {
#if __has_builtin(__builtin_amdgcn_permlane32_swap)
    uint2v r = __builtin_amdgcn_permlane32_swap(__float_as_uint(v), __float_as_uint(v), false, false);
    return __uint_as_float(r.x ^ r.y ^ __float_as_uint(v));
#else
    float a = v, b = v;
    asm volatile("v_permlane32_swap_b32 %0, %1" : "+v"(a), "+v"(b));
    return __uint_as_float(__float_as_uint(a) ^ __float_as_uint(b) ^ __float_as_uint(v));
#endif
}

// packed complex update: returns e1.x*A + (-e2.x,e2.y)"swap"(A) + e1.z*B + swap-term(B)
//   out.lo = e1.x*A.x + e2.x*A.y + e1.z*B.x + e2.z*B.y     (e2.x = -imag)
//   out.hi = e1.x*A.y + e2.y*A.x + e1.z*B.y + e2.w*B.x
// i.e. complex (c_own * A + c_par * B) with c_own=(e1.x, e2.y), c_par=(e1.z, e2.w).
__device__ __forceinline__ float2 pk_cplx(float4 e1, float4 e2, float2 A, float2 B) {
    float2 t;
    float2 e1xy = make_float2(e1.x, e1.y), e1zw = make_float2(e1.z, e1.w);
    float2 e2xy = make_float2(e2.x, e2.y), e2zw = make_float2(e2.z, e2.w);
    asm("v_pk_mul_f32 %0, %1, %2 op_sel:[0,0] op_sel_hi:[0,1]"
        : "=v"(t) : "v"(e1xy), "v"(A));                       // [ar*Ar, ar*Ai]
    asm("v_pk_fma_f32 %0, %1, %2, %0 op_sel:[0,1,0] op_sel_hi:[1,0,1]"
        : "+v"(t) : "v"(e2xy), "v"(A));                       // +[-ai*Ai, ai*Ar]
    asm("v_pk_fma_f32 %0, %1, %2, %0 op_sel:[0,0,0] op_sel_hi:[0,1,1]"
        : "+v"(t) : "v"(e1zw), "v"(B));                       // +[br*Br, br*Bi]
    asm("v_pk_fma_f32 %0, %1, %2, %0 op_sel:[0,1,0] op_sel_hi:[1,0,1]"
        : "+v"(t) : "v"(e2zw), "v"(B));                       // +[-bi*Bi, bi*Br]
    return t;
}

// LDS bank swizzles (16-lane-phase model; carried from r7 — conflicts 335K)
#define F0SWZ(x) ((x) ^ (((x) >> 4) & 3) ^ ((((x) >> 10) & 3) << 2))
__device__ __forceinline__ int f1swz(unsigned int pack, int x) {
    int low = 0;
#pragma unroll
    for (int k = 0; k < 8; ++k)
        low ^= (-((x >> (4 + k)) & 1)) & (int)((pack >> (4 * k)) & 15u);
    return x ^ low;
}

// ---------------------------------------------------------------------------
// Kernel 2: fused reduce+GELU+norm + quantum circuit. 1024 threads, 4 amps.
// M0: state = (wv<<8)|(l6<<2)|j. Two transitions/layer (T: buf0, T': buf1+CNOT).
// All gate math via v_pk_fma_f32 packed complex ops (4 instr per 2x2 apply).
// ---------------------------------------------------------------------------
__global__ __launch_bounds__(1024) void circuit_kernel(
    const float* __restrict__ psum, int splitk, const float* __restrict__ bias,
    const float* __restrict__ qw, const float* __restrict__ Wfc,
    const float* __restrict__ bfc, float* __restrict__ out)
{
    __shared__ float2 sbuf[2][4096];   // 64 KB: buf0 for T, buf1 for T'
    __shared__ float4 ge[48][2][2];    // [g][sel][k]: packed-coef quads
    __shared__ float redw[16];
    __shared__ float zred[16][12];
    __shared__ float zbit[12];

    const int t = threadIdx.x;
    const int b = blockIdx.x;
    const int wv = t >> 6;
    const int l6 = t & 63;
    const int w01 = wv & 3;
    const int w23 = wv >> 2;

    const unsigned int APACK[4] = {0x84000031u, 0x84000013u, 0x84010021u, 0x84008432u};

    if (t < 48) {
        const int base = t * 3;
        const float phi = qw[base + 0], th = qw[base + 1], om = qw[base + 2];
        float c, s, chp, shp, chm, shm;
        sincosf(0.5f * th, &s, &c);
        sincosf(0.5f * (phi + om), &shp, &chp);
        sincosf(0.5f * (phi - om), &shm, &chm);
        const float u00r =  c * chp, u00i = -c * shp;
        const float u01r = -s * chm, u01i = -s * shm;
        const float u10r =  s * chm, u10i = -s * shm;
        const float u11r =  c * chp, u11i =  c * shp;
        // sel 0: (own=u00, par=u01)  — lane bsel=0 / reg row0 (A=j0,B=j1)
        ge[t][0][0] = make_float4(u00r, 0.f, u01r, 0.f);
        ge[t][0][1] = make_float4(-u00i, u00i, -u01i, u01i);
        // sel 1: (own=u11, par=u10)  — lane bsel=1 / reg row1 (call with B,A)
        ge[t][1][0] = make_float4(u11r, 0.f, u10r, 0.f);
        ge[t][1][1] = make_float4(-u11i, u11i, -u10i, u10i);
    }

    // per-thread CNOT-perm images (f1_l-transformed), registers, static-indexed
    int ssfb[4], sspjv[4][4], fwb[4];
    const int s0base = (wv << 8) | (l6 << 2);
    const int s1base = ((l6 & 3) << 10) | ((l6 >> 2) << 4) | (w23 << 2) | w01;
#pragma unroll
    for (int ll = 0; ll < 4; ++ll) {
        const int r = ll + 1;
        int u = s0base;
        for (int q = 11; q >= 0; --q) {
            const int bc = 11 - q, bt2 = 11 - ((q + r) % 12);
            u ^= ((u >> bc) & 1) << bt2;
        }
        ssfb[ll] = f1swz(APACK[ll], u);
        fwb[ll]  = f1swz(APACK[ll], s1base);
        sspjv[ll][0] = 0;
#pragma unroll
        for (int j = 1; j < 4; ++j) {
            int v = j;
            for (int q = 11; q >= 0; --q) {
                const int bc = 11 - q, bt2 = 11 - ((q + r) % 12);
                v ^= ((v >> bc) & 1) << bt2;
            }
            sspjv[ll][j] = f1swz(APACK[ll], v);
        }
    }

    const int base0 = F0SWZ(s0base);   // T write: base0 ^ j
    const int base1 = F0SWZ(s1base);   // T read:  base1 ^ (j<<8)

    const int bs0 = l6 & 1, bs1 = (l6 >> 1) & 1, bs2 = (l6 >> 2) & 1;
    const int bs3 = (l6 >> 3) & 1, bs4 = (l6 >> 4) & 1, bs5 = (l6 >> 5) & 1;

    // ---- fused split-K reduce + bias + exact GELU + norm ----
    float a0 = 0.f, a1 = 0.f, a2 = 0.f, a3 = 0.f;
    for (int z = 0; z < splitk; ++z) {
        const float4 p = *(const float4*)(psum + (size_t)z * ZSTR + (size_t)b * DIM + t * 4);
        a0 += p.x; a1 += p.y; a2 += p.z; a3 += p.w;
    }
    {
        const float4 bb = *(const float4*)(bias + t * 4);
        a0 += bb.x; a1 += bb.y; a2 += bb.z; a3 += bb.w;
    }
    float xr[4];
    xr[0] = 0.5f * a0 * (1.0f + erff(a0 * 0.70710678118654752f));
    xr[1] = 0.5f * a1 * (1.0f + erff(a1 * 0.70710678118654752f));
    xr[2] = 0.5f * a2 * (1.0f + erff(a2 * 0.70710678118654752f));
    xr[3] = 0.5f * a3 * (1.0f + erff(a3 * 0.70710678118654752f));
    float ss = xr[0]*xr[0] + xr[1]*xr[1] + xr[2]*xr[2] + xr[3]*xr[3];
#pragma unroll
    for (int off = 32; off; off >>= 1) ss += __shfl_xor(ss, off);
    if (l6 == 0) redw[wv] = ss;
    __syncthreads();
    float tot = 0.f;
#pragma unroll
    for (int i = 0; i < 16; ++i) tot += redw[i];
    const float rn = 1.0f / sqrtf(tot);

    float2 S[4];
#pragma unroll
    for (int j = 0; j < 4; ++j) S[j] = make_float2(xr[j] * rn, 0.f);

    auto lane_gate = [&](auto&& partner, float4 e1, float4 e2) {
#pragma unroll
        for (int j = 0; j < 4; ++j) {
            float2 P = make_float2(partner(S[j].x), partner(S[j].y));
            S[j] = pk_cplx(e1, e2, S[j], P);
        }
    };
    auto reg_gate = [&](int lb, float4 e10, float4 e20, float4 e11, float4 e21) {
#pragma unroll
        for (int p = 0; p < 2; ++p) {
            const int j0 = (lb == 0) ? (p << 1) : p;
            const int j1 = j0 | (1 << lb);
            const float2 A = S[j0], B = S[j1];
            S[j0] = pk_cplx(e10, e20, A, B);
            S[j1] = pk_cplx(e11, e21, B, A);   // row1 stored as (u11,u10): swap args
        }
    };

    for (int rep = 0; rep < 4; ++rep) {
#pragma unroll
        for (int l = 0; l < 4; ++l) {
            const int gb = l * 12;
            // ---- epoch A (M0): lane gates b2..b7 (q9..q4), reg b0,b1 (q11,q10)
            lane_gate([](float v) { return fdpp<0xB1>(v); },               ge[gb + 9][bs0][0], ge[gb + 9][bs0][1]);
            lane_gate([](float v) { return fdpp<0x4E>(v); },               ge[gb + 8][bs1][0], ge[gb + 8][bs1][1]);
            lane_gate([](float v) { return fdpp<0x1B>(fdpp<0x141>(v)); },  ge[gb + 7][bs2][0], ge[gb + 7][bs2][1]);
            lane_gate([](float v) { return fdpp<0x141>(fdpp<0x140>(v)); }, ge[gb + 6][bs3][0], ge[gb + 6][bs3][1]);
            lane_gate([](float v) { return pl16_partner(v); },             ge[gb + 5][bs4][0], ge[gb + 5][bs4][1]);
            lane_gate([](float v) { return pl32_partner(v); },             ge[gb + 4][bs5][0], ge[gb + 4][bs5][1]);
            reg_gate(0, ge[gb + 11][0][0], ge[gb + 11][0][1], ge[gb + 11][1][0], ge[gb + 11][1][1]);
            reg_gate(1, ge[gb + 10][0][0], ge[gb + 10][0][1], ge[gb + 10][1][0], ge[gb + 10][1][1]);
            // ---- T: M0 -> M1 (buf0, f0) ----
#pragma unroll
            for (int j = 0; j < 4; ++j)
                sbuf[0][base0 ^ j] = S[j];
            __syncthreads();
#pragma unroll
            for (int j = 0; j < 4; ++j)
                S[j] = sbuf[0][base1 ^ (j << 8)];
            // ---- epoch B (M1): DPP gates b10(q1),b11(q0); reg b8(q3),b9(q2)
            lane_gate([](float v) { return fdpp<0xB1>(v); }, ge[gb + 1][bs0][0], ge[gb + 1][bs0][1]);
            lane_gate([](float v) { return fdpp<0x4E>(v); }, ge[gb + 0][bs1][0], ge[gb + 0][bs1][1]);
            reg_gate(0, ge[gb + 3][0][0], ge[gb + 3][0][1], ge[gb + 3][1][0], ge[gb + 3][1][1]);
            reg_gate(1, ge[gb + 2][0][0], ge[gb + 2][0][1], ge[gb + 2][1][0], ge[gb + 2][1][1]);
            // ---- T': M1 -> M0 + CNOT fold (buf1, f1_l) ----
#pragma unroll
            for (int j = 0; j < 4; ++j)
                sbuf[1][fwb[l] ^ (j << 8) ^ ((l == 2) ? (j & 1) : 0)] = S[j];
            __syncthreads();
#pragma unroll
            for (int j = 0; j < 4; ++j)
                S[j] = sbuf[1][ssfb[l] ^ sspjv[l][j]];
        }
    }

    // ---- <Z_bp> partials (M0: bits >=2 thread-uniform, d = t*4+j) ----
    const float p0 = S[0].x*S[0].x + S[0].y*S[0].y;
    const float p1 = S[1].x*S[1].x + S[1].y*S[1].y;
    const float p2 = S[2].x*S[2].x + S[2].y*S[2].y;
    const float p3 = S[3].x*S[3].x + S[3].y*S[3].y;
    const float psumv = p0 + p1 + p2 + p3;
    float zp[12];
    zp[0] = p0 - p1 + p2 - p3;
    zp[1] = p0 + p1 - p2 - p3;
#pragma unroll
    for (int bp = 2; bp < 12; ++bp)
        zp[bp] = ((t >> (bp - 2)) & 1) ? -psumv : psumv;
#pragma unroll
    for (int bp = 0; bp < 12; ++bp) {
        float vv = zp[bp];
#pragma unroll
        for (int off = 32; off; off >>= 1) vv += __shfl_xor(vv, off);
        if (l6 == 0) zred[wv][bp] = vv;
    }
    __syncthreads();
    if (t < 12) {
        float vv = 0.f;
#pragma unroll
        for (int w2 = 0; w2 < 16; ++w2) vv += zred[w2][t];
        zbit[t] = vv;
    }
    __syncthreads();
    if (t < 10) {
        float o = bfc[t];
#pragma unroll
        for (int q = 0; q < NQ; ++q) o = fmaf(zbit[11 - q], Wfc[t * NQ + q], o);
        out[b * 10 + t] = o;
    }
}

extern "C" void kernel_launch(void* const* d_in, const int* in_sizes, int n_in,
                              void* d_out, int out_size, void* d_ws, size_t ws_size,
                              hipStream_t stream)
{
    const float* inputs = (const float*)d_in[0];   // 128 x 4096
    const float* W_pre  = (const float*)d_in[1];   // 4096 x 4096
    const float* b_pre  = (const float*)d_in[2];   // 4096
    const float* q_w    = (const float*)d_in[3];   // 4 x 12 x 3
    const float* W_fc   = (const float*)d_in[4];   // 10 x 12
    const float* b_fc   = (const float*)d_in[5];   // 10
    float* outp = (float*)d_out;                   // 128 x 10
    float* psum = (float*)d_ws;                    // splitk x 128 x 4096 f32

    const size_t slab = (size_t)ZSTR * sizeof(float);   // 2 MB
    int splitk = 8;
    if (ws_size < 8 * slab) splitk = 4;
    if (ws_size < 4 * slab) splitk = 2;
    if (ws_size < 2 * slab) splitk = 1;

    dim3 g1(DIM / BN, splitk);
    gemm_bf16_kernel<<<g1, 256, 0, stream>>>(inputs, W_pre, psum, splitk);
    circuit_kernel<<<BATCH, 1024, 0, stream>>>(psum, splitk, b_pre, q_w, W_fc, b_fc, outp);
}

// Round 10
// 93.690 us; speedup vs baseline: 1.1622x; 1.1190x over previous
//
#include <hip/hip_runtime.h>
#include <hip/hip_bf16.h>
#include <math.h>

#define DIM 4096
#define NQ 12
#define BATCH 128
#define BN 32
#define BK 64
#define ZSTR (128 * DIM)   // floats per split-k slab

typedef __attribute__((ext_vector_type(8))) short bf16x8;
typedef __attribute__((ext_vector_type(4))) float f32x4;
typedef unsigned int uint2v __attribute__((ext_vector_type(2)));

// pair-convert f32x4 -> 4 bf16 via v_cvt_pk_bf16_f32 (RNE)
__device__ __forceinline__ uint2 cvt4bf(float4 v) {
    union { __hip_bfloat162 h2[2]; uint2 u; } pk;
    pk.h2[0] = __float22bfloat162_rn(make_float2(v.x, v.y));
    pk.h2[1] = __float22bfloat162_rn(make_float2(v.z, v.w));
    return pk.u;
}

// ---------------------------------------------------------------------------
// Kernel 1: split-K bf16 MFMA GEMM with register prefetch double-buffering.
// psum[z][m][n] = A[m, kz] @ W[n, kz]^T ; BM=128, BN=32, BK=64, 4 waves.
// ---------------------------------------------------------------------------
__global__ __launch_bounds__(256) void gemm_bf16_kernel(
    const float* __restrict__ A, const float* __restrict__ W,
    float* __restrict__ psum, int splitk)
{
    __shared__ unsigned short As[128][BK + 8];
    __shared__ unsigned short Bs[BN][BK + 8];

    const int t  = threadIdx.x;
    const int bn = blockIdx.x * BN;
    const int z  = blockIdx.y;
    const int krange = DIM / splitk;
    const int kstart = z * krange;
    const int kend = kstart + krange;
    const int w = t >> 6;
    const int l = t & 63;
    const int m0w = w * 32;

    f32x4 acc[2][2] = {};
    float4 pa[8], pb[2];

    auto load_tiles = [&](int k0) {
#pragma unroll
        for (int i = 0; i < 8; ++i) {
            const int fid = t + i * 256;
            pa[i] = *(const float4*)(A + (size_t)(fid >> 4) * DIM + k0 + (fid & 15) * 4);
        }
#pragma unroll
        for (int i = 0; i < 2; ++i) {
            const int fid = t + i * 256;
            pb[i] = *(const float4*)(W + (size_t)(bn + (fid >> 4)) * DIM + k0 + (fid & 15) * 4);
        }
    };

    load_tiles(kstart);
    for (int k0 = kstart; k0 < kend; k0 += BK) {
        __syncthreads();
#pragma unroll
        for (int i = 0; i < 8; ++i) {
            const int fid = t + i * 256;
            *(uint2*)&As[fid >> 4][(fid & 15) * 4] = cvt4bf(pa[i]);
        }
#pragma unroll
        for (int i = 0; i < 2; ++i) {
            const int fid = t + i * 256;
            *(uint2*)&Bs[fid >> 4][(fid & 15) * 4] = cvt4bf(pb[i]);
        }
        const int kn = (k0 + BK < kend) ? (k0 + BK) : k0;
        load_tiles(kn);
        __syncthreads();
#pragma unroll
        for (int kk = 0; kk < 2; ++kk) {
            const int kc = kk * 32 + (l >> 4) * 8;
            bf16x8 a0 = *(const bf16x8*)&As[m0w +      (l & 15)][kc];
            bf16x8 a1 = *(const bf16x8*)&As[m0w + 16 + (l & 15)][kc];
            bf16x8 b0 = *(const bf16x8*)&Bs[      (l & 15)][kc];
            bf16x8 b1 = *(const bf16x8*)&Bs[16 + (l & 15)][kc];
            acc[0][0] = __builtin_amdgcn_mfma_f32_16x16x32_bf16(a0, b0, acc[0][0], 0, 0, 0);
            acc[0][1] = __builtin_amdgcn_mfma_f32_16x16x32_bf16(a0, b1, acc[0][1], 0, 0, 0);
            acc[1][0] = __builtin_amdgcn_mfma_f32_16x16x32_bf16(a1, b0, acc[1][0], 0, 0, 0);
            acc[1][1] = __builtin_amdgcn_mfma_f32_16x16x32_bf16(a1, b1, acc[1][1], 0, 0, 0);
        }
    }
#pragma unroll
    for (int mf = 0; mf < 2; ++mf)
#pragma unroll
        for (int nf = 0; nf < 2; ++nf)
#pragma unroll
            for (int r = 0; r < 4; ++r) {
                const int m = m0w + mf * 16 + (l >> 4) * 4 + r;
                const int n = bn + nf * 16 + (l & 15);
                psum[(size_t)z * ZSTR + (size_t)m * DIM + n] = acc[mf][nf][r];
            }
}

// ---------------------------------------------------------------------------
// lane-exchange primitives (VALU pipe, zero DS)
// ---------------------------------------------------------------------------
template<int CTRL>
__device__ __forceinline__ float fdpp(float v) {
    return __int_as_float(__builtin_amdgcn_update_dpp(
        0, __float_as_int(v), CTRL, 0xF, 0xF, false));
}
__device__ __forceinline__ float pl16_partner(float v) {
#if __has_builtin(__builtin_amdgcn_permlane16_swap)
    uint2v r = __builtin_amdgcn_permlane16_swap(__float_as_uint(v), __float_as_uint(v), false, false);
    return __uint_as_float(r.x ^ r.y ^ __float_as_uint(v));
#else
    float a = v, b = v;
    asm volatile("v_permlane16_swap_b32 %0, %1" : "+v"(a), "+v"(b));
    return __uint_as_float(__float_as_uint(a) ^ __float_as_uint(b) ^ __float_as_uint(v));
#endif
}
__device__ __forceinline__ float pl32_partner(float v) {
#if __has_builtin(__builtin_amdgcn_permlane32_swap)
    uint2v r = __builtin_amdgcn_permlane32_swap(__float_as_uint(v), __float_as_uint(v), false, false);
    return __uint_as_float(r.x ^ r.y ^ __float_as_uint(v));
#else
    float a = v, b = v;
    asm volatile("v_permlane32_swap_b32 %0, %1" : "+v"(a), "+v"(b));
    return __uint_as_float(__float_as_uint(a) ^ __float_as_uint(b) ^ __float_as_uint(v));
#endif
}

// derive (-ci, ci) from (cr, ci) — plain C (r9's asm version had a wrong
// op_sel_hi and produced (-ci,-ci); one v_xor + pack, runs once per gate)
__device__ __forceinline__ float2 negpair(float2 c) {
    return make_float2(-c.y, c.y);
}
// complex update: own*A + par*B (own=(or,oi), ownN=(-oi,oi), etc.)
// op_sel patterns identical to round-8's PASSING kernel.
__device__ __forceinline__ float2 pk_cplx(float2 own, float2 ownN, float2 par, float2 parN,
                                          float2 A, float2 B) {
    float2 t;
    asm("v_pk_mul_f32 %0, %1, %2 op_sel:[0,0] op_sel_hi:[0,1]"
        : "=v"(t) : "v"(own), "v"(A));            // [or*Ar, or*Ai]
    asm("v_pk_fma_f32 %0, %1, %2, %0 op_sel:[0,1,0] op_sel_hi:[1,0,1]"
        : "+v"(t) : "v"(ownN), "v"(A));           // +[-oi*Ai, oi*Ar]
    asm("v_pk_fma_f32 %0, %1, %2, %0 op_sel:[0,0,0] op_sel_hi:[0,1,1]"
        : "+v"(t) : "v"(par), "v"(B));            // +[pr*Br, pr*Bi]
    asm("v_pk_fma_f32 %0, %1, %2, %0 op_sel:[0,1,0] op_sel_hi:[1,0,1]"
        : "+v"(t) : "v"(parN), "v"(B));           // +[-pi*Bi, pi*Br]
    return t;
}

// LDS bank swizzles (16-lane-phase model; r7 — conflicts ~335K)
#define F0SWZ(x) ((x) ^ (((x) >> 4) & 3) ^ ((((x) >> 10) & 3) << 2))
__device__ __forceinline__ int f1swz(unsigned int pack, int x) {
    int low = 0;
#pragma unroll
    for (int k = 0; k < 8; ++k)
        low ^= (-((x >> (4 + k)) & 1)) & (int)((pack >> (4 * k)) & 15u);
    return x ^ low;
}

// ---------------------------------------------------------------------------
// Kernel 2: fused reduce+GELU+norm + quantum circuit. 1024 threads, 4 amps.
// M0: state = (wv<<8)|(l6<<2)|j. Two transitions/layer (T: buf0, T': buf1+CNOT).
// Coefficients: ge4[gate][sel] = (own_r,own_i,par_r,par_i); lane gates fold the
// bsel into the LDS address -> ONE ds_read_b128 per lane gate (was two).
// ---------------------------------------------------------------------------
__global__ __launch_bounds__(1024) void circuit_kernel(
    const float* __restrict__ psum, int splitk, const float* __restrict__ bias,
    const float* __restrict__ qw, const float* __restrict__ Wfc,
    const float* __restrict__ bfc, float* __restrict__ out)
{
    __shared__ float2 sbuf[2][4096];   // 64 KB: buf0 for T, buf1 for T'
    __shared__ float4 ge4[48][2];      // [gate][sel]: sel0=(u00,u01) sel1=(u11,u10)
    __shared__ float redw[16];
    __shared__ float zred[16][12];
    __shared__ float zbit[12];

    const int t = threadIdx.x;
    const int b = blockIdx.x;
    const int wv = t >> 6;
    const int l6 = t & 63;
    const int w01 = wv & 3;
    const int w23 = wv >> 2;

    const unsigned int APACK[4] = {0x84000031u, 0x84000013u, 0x84010021u, 0x84008432u};

    if (t < 48) {
        const int base = t * 3;
        const float phi = qw[base + 0], th = qw[base + 1], om = qw[base + 2];
        float c, s, chp, shp, chm, shm;
        sincosf(0.5f * th, &s, &c);
        sincosf(0.5f * (phi + om), &shp, &chp);
        sincosf(0.5f * (phi - om), &shm, &chm);
        const float u00r =  c * chp, u00i = -c * shp;
        const float u01r = -s * chm, u01i = -s * shm;
        const float u10r =  s * chm, u10i = -s * shm;
        const float u11r =  c * chp, u11i =  c * shp;
        ge4[t][0] = make_float4(u00r, u00i, u01r, u01i);   // own=u00, par=u01
        ge4[t][1] = make_float4(u11r, u11i, u10r, u10i);   // own=u11, par=u10
    }

    // per-thread CNOT-perm images (f1_l-transformed), registers, static-indexed
    int ssfb[4], sspjv[4][4], fwb[4];
    const int s0base = (wv << 8) | (l6 << 2);
    const int s1base = ((l6 & 3) << 10) | ((l6 >> 2) << 4) | (w23 << 2) | w01;
#pragma unroll
    for (int ll = 0; ll < 4; ++ll) {
        const int r = ll + 1;
        int u = s0base;
        for (int q = 11; q >= 0; --q) {
            const int bc = 11 - q, bt2 = 11 - ((q + r) % 12);
            u ^= ((u >> bc) & 1) << bt2;
        }
        ssfb[ll] = f1swz(APACK[ll], u);
        fwb[ll]  = f1swz(APACK[ll], s1base);
        sspjv[ll][0] = 0;
#pragma unroll
        for (int j = 1; j < 4; ++j) {
            int v = j;
            for (int q = 11; q >= 0; --q) {
                const int bc = 11 - q, bt2 = 11 - ((q + r) % 12);
                v ^= ((v >> bc) & 1) << bt2;
            }
            sspjv[ll][j] = f1swz(APACK[ll], v);
        }
    }

    const int base0 = F0SWZ(s0base);   // T write: base0 ^ j
    const int base1 = F0SWZ(s1base);   // T read:  base1 ^ (j<<8)

    const int bs0 = l6 & 1, bs1 = (l6 >> 1) & 1, bs2 = (l6 >> 2) & 1;
    const int bs3 = (l6 >> 3) & 1, bs4 = (l6 >> 4) & 1, bs5 = (l6 >> 5) & 1;

    // ---- fused split-K reduce + bias + exact GELU + norm ----
    float a0 = 0.f, a1 = 0.f, a2 = 0.f, a3 = 0.f;
    for (int z = 0; z < splitk; ++z) {
        const float4 p = *(const float4*)(psum + (size_t)z * ZSTR + (size_t)b * DIM + t * 4);
        a0 += p.x; a1 += p.y; a2 += p.z; a3 += p.w;
    }
    {
        const float4 bb = *(const float4*)(bias + t * 4);
        a0 += bb.x; a1 += bb.y; a2 += bb.z; a3 += bb.w;
    }
    float xr[4];
    xr[0] = 0.5f * a0 * (1.0f + erff(a0 * 0.70710678118654752f));
    xr[1] = 0.5f * a1 * (1.0f + erff(a1 * 0.70710678118654752f));
    xr[2] = 0.5f * a2 * (1.0f + erff(a2 * 0.70710678118654752f));
    xr[3] = 0.5f * a3 * (1.0f + erff(a3 * 0.70710678118654752f));
    float ss = xr[0]*xr[0] + xr[1]*xr[1] + xr[2]*xr[2] + xr[3]*xr[3];
#pragma unroll
    for (int off = 32; off; off >>= 1) ss += __shfl_xor(ss, off);
    if (l6 == 0) redw[wv] = ss;
    __syncthreads();
    float tot = 0.f;
#pragma unroll
    for (int i = 0; i < 16; ++i) tot += redw[i];
    const float rn = 1.0f / sqrtf(tot);

    float2 S[4];
#pragma unroll
    for (int j = 0; j < 4; ++j) S[j] = make_float2(xr[j] * rn, 0.f);

    auto lane_gate = [&](auto&& partner, float4 cf) {
        const float2 own = make_float2(cf.x, cf.y), par = make_float2(cf.z, cf.w);
        const float2 ownN = negpair(own), parN = negpair(par);
#pragma unroll
        for (int j = 0; j < 4; ++j) {
            float2 P = make_float2(partner(S[j].x), partner(S[j].y));
            S[j] = pk_cplx(own, ownN, par, parN, S[j], P);
        }
    };
    auto reg_gate = [&](int lb, float4 r0, float4 r1) {
        const float2 o0 = make_float2(r0.x, r0.y), p0 = make_float2(r0.z, r0.w);
        const float2 o1 = make_float2(r1.x, r1.y), p1 = make_float2(r1.z, r1.w);
        const float2 o0N = negpair(o0), p0N = negpair(p0);
        const float2 o1N = negpair(o1), p1N = negpair(p1);
#pragma unroll
        for (int p = 0; p < 2; ++p) {
            const int j0 = (lb == 0) ? (p << 1) : p;
            const int j1 = j0 | (1 << lb);
            const float2 A = S[j0], B = S[j1];
            S[j0] = pk_cplx(o0, o0N, p0, p0N, A, B);
            S[j1] = pk_cplx(o1, o1N, p1, p1N, B, A);   // row1 = (u11,u10): swap args
        }
    };

    for (int rep = 0; rep < 4; ++rep) {
#pragma unroll
        for (int l = 0; l < 4; ++l) {
            const int gb = l * 12;
            // ---- epoch A (M0): lane gates b2..b7 (q9..q4), reg b0,b1 (q11,q10)
            lane_gate([](float v) { return fdpp<0xB1>(v); },               ge4[gb + 9][bs0]);
            lane_gate([](float v) { return fdpp<0x4E>(v); },               ge4[gb + 8][bs1]);
            lane_gate([](float v) { return fdpp<0x1B>(fdpp<0x141>(v)); },  ge4[gb + 7][bs2]);
            lane_gate([](float v) { return fdpp<0x141>(fdpp<0x140>(v)); }, ge4[gb + 6][bs3]);
            lane_gate([](float v) { return pl16_partner(v); },             ge4[gb + 5][bs4]);
            lane_gate([](float v) { return pl32_partner(v); },             ge4[gb + 4][bs5]);
            reg_gate(0, ge4[gb + 11][0], ge4[gb + 11][1]);
            reg_gate(1, ge4[gb + 10][0], ge4[gb + 10][1]);
            // ---- T: M0 -> M1 (buf0, f0) ----
#pragma unroll
            for (int j = 0; j < 4; ++j)
                sbuf[0][base0 ^ j] = S[j];
            __syncthreads();
#pragma unroll
            for (int j = 0; j < 4; ++j)
                S[j] = sbuf[0][base1 ^ (j << 8)];
            // ---- epoch B (M1): DPP gates b10(q1),b11(q0); reg b8(q3),b9(q2)
            lane_gate([](float v) { return fdpp<0xB1>(v); }, ge4[gb + 1][bs0]);
            lane_gate([](float v) { return fdpp<0x4E>(v); }, ge4[gb + 0][bs1]);
            reg_gate(0, ge4[gb + 3][0], ge4[gb + 3][1]);
            reg_gate(1, ge4[gb + 2][0], ge4[gb + 2][1]);
            // ---- T': M1 -> M0 + CNOT fold (buf1, f1_l) ----
#pragma unroll
            for (int j = 0; j < 4; ++j)
                sbuf[1][fwb[l] ^ (j << 8) ^ ((l == 2) ? (j & 1) : 0)] = S[j];
            __syncthreads();
#pragma unroll
            for (int j = 0; j < 4; ++j)
                S[j] = sbuf[1][ssfb[l] ^ sspjv[l][j]];
        }
    }

    // ---- <Z_bp> partials (M0: bits >=2 thread-uniform, d = t*4+j) ----
    const float p0 = S[0].x*S[0].x + S[0].y*S[0].y;
    const float p1 = S[1].x*S[1].x + S[1].y*S[1].y;
    const float p2 = S[2].x*S[2].x + S[2].y*S[2].y;
    const float p3 = S[3].x*S[3].x + S[3].y*S[3].y;
    const float psumv = p0 + p1 + p2 + p3;
    float zp[12];
    zp[0] = p0 - p1 + p2 - p3;
    zp[1] = p0 + p1 - p2 - p3;
#pragma unroll
    for (int bp = 2; bp < 12; ++bp)
        zp[bp] = ((t >> (bp - 2)) & 1) ? -psumv : psumv;
#pragma unroll
    for (int bp = 0; bp < 12; ++bp) {
        float vv = zp[bp];
#pragma unroll
        for (int off = 32; off; off >>= 1) vv += __shfl_xor(vv, off);
        if (l6 == 0) zred[wv][bp] = vv;
    }
    __syncthreads();
    if (t < 12) {
        float vv = 0.f;
#pragma unroll
        for (int w2 = 0; w2 < 16; ++w2) vv += zred[w2][t];
        zbit[t] = vv;
    }
    __syncthreads();
    if (t < 10) {
        float o = bfc[t];
#pragma unroll
        for (int q = 0; q < NQ; ++q) o = fmaf(zbit[11 - q], Wfc[t * NQ + q], o);
        out[b * 10 + t] = o;
    }
}

extern "C" void kernel_launch(void* const* d_in, const int* in_sizes, int n_in,
                              void* d_out, int out_size, void* d_ws, size_t ws_size,
                              hipStream_t stream)
{
    const float* inputs = (const float*)d_in[0];   // 128 x 4096
    const float* W_pre  = (const float*)d_in[1];   // 4096 x 4096
    const float* b_pre  = (const float*)d_in[2];   // 4096
    const float* q_w    = (const float*)d_in[3];   // 4 x 12 x 3
    const float* W_fc   = (const float*)d_in[4];   // 10 x 12
    const float* b_fc   = (const float*)d_in[5];   // 10
    float* outp = (float*)d_out;                   // 128 x 10
    float* psum = (float*)d_ws;                    // splitk x 128 x 4096 f32

    const size_t slab = (size_t)ZSTR * sizeof(float);   // 2 MB
    int splitk = 8;
    if (ws_size < 8 * slab) splitk = 4;
    if (ws_size < 4 * slab) splitk = 2;
    if (ws_size < 2 * slab) splitk = 1;

    dim3 g1(DIM / BN, splitk);
    gemm_bf16_kernel<<<g1, 256, 0, stream>>>(inputs, W_pre, psum, splitk);
    circuit_kernel<<<BATCH, 1024, 0, stream>>>(psum, splitk, b_pre, q_w, W_fc, b_fc, outp);
}